// Round 4
// baseline (3529.941 us; speedup 1.0000x reference)
//
#include <hip/hip_runtime.h>

#define BATCH 256
#define TT 512
#define CIN 512
#define UU 512
#define ZN 2048
#define BT (BATCH*TT)
#define NWGPB 16   // WGs per batch-group barrier

typedef __attribute__((ext_vector_type(8))) short short8;
typedef __attribute__((ext_vector_type(4))) float f32x4;

__device__ __forceinline__ short f2bf(float f){
  unsigned u = __float_as_uint(f);
  u += 0x7fffu + ((u >> 16) & 1u);   // round-to-nearest-even
  return (short)(u >> 16);
}
__device__ __forceinline__ float bf2f(unsigned short s){
  unsigned u = ((unsigned)s) << 16;
  return __uint_as_float(u);
}

#define GLD16(g, l) __builtin_amdgcn_global_load_lds( \
    (const __attribute__((address_space(1))) void*)(g), \
    (__attribute__((address_space(3))) void*)(l), 16, 0, 0)

// coherent (device-scope, MALL) 16B load with immediate offset
#define CLOAD(dst, p, OFFSTR) asm volatile( \
    "global_load_dwordx4 %0, %1, off offset:" OFFSTR " sc0 sc1" \
    : "=v"(dst) : "v"(p) : "memory")
// coherent 4B load
#define CLOADW(dst, p) asm volatile( \
    "global_load_dword %0, %1, off sc0 sc1" \
    : "=v"(dst) : "v"(p) : "memory")

__device__ __forceinline__ void st_coh_u16(void* p, unsigned v){
  asm volatile("global_store_short %0, %1, off sc0 sc1" :: "v"(p), "v"(v) : "memory");
}
__device__ __forceinline__ void st_coh_u32(void* p, unsigned v){
  asm volatile("global_store_dword %0, %1, off sc0 sc1" :: "v"(p), "v"(v) : "memory");
}

__device__ __forceinline__ float sigm(float x){ return 1.0f/(1.0f + __expf(-x)); }
__device__ __forceinline__ float tanh_fast(float x){ return 1.0f - 2.0f/(1.0f + __expf(2.0f*x)); }

// ---------------- convert x [B][T][C] f32 -> x_tb [(t*B+b)][C] bf16 ----------------
__global__ __launch_bounds__(256) void convert_x_kernel(const float* __restrict__ x,
                                                        short* __restrict__ xb){
  const long total = (long)TT*BATCH*64;   // 8-elem chunks
  const long stride = (long)gridDim.x * blockDim.x;
  for (long i = (long)blockIdx.x * blockDim.x + threadIdx.x; i < total; i += stride){
    const int c8 = (int)(i & 63);
    const long tb = i >> 6;
    const int b = (int)(tb & (BATCH-1));
    const int t = (int)(tb >> 8);
    const float* src = x + ((long)b*TT + t)*CIN + c8*8;
    const float4 v0 = *(const float4*)(src);
    const float4 v1 = *(const float4*)(src + 4);
    short8 o;
    o[0]=f2bf(v0.x); o[1]=f2bf(v0.y); o[2]=f2bf(v0.z); o[3]=f2bf(v0.w);
    o[4]=f2bf(v1.x); o[5]=f2bf(v1.y); o[6]=f2bf(v1.z); o[7]=f2bf(v1.w);
    *(short8*)(xb + i*8) = o;
  }
}

// ---------------- transpose wx/wh: [512][2048] f32 -> [2048][512] bf16 ----------------
__global__ __launch_bounds__(256) void transpose_w_kernel(
    const float* __restrict__ wx, const float* __restrict__ wh,
    short* __restrict__ wxt, short* __restrict__ wht){
  const float* src = blockIdx.z ? wh : wx;
  short* dst = blockIdx.z ? wht : wxt;
  __shared__ float tile[32][33];
  const int nt = blockIdx.x << 5;
  const int kt = blockIdx.y << 5;
  const int tx = threadIdx.x & 31, ty = threadIdx.x >> 5;
  #pragma unroll
  for (int i = 0; i < 32; i += 8)
    tile[ty+i][tx] = src[(long)(kt+ty+i)*ZN + nt+tx];
  __syncthreads();
  #pragma unroll
  for (int i = 0; i < 32; i += 8)
    dst[(long)(nt+ty+i)*512 + kt+tx] = f2bf(tile[tx][ty+i]);
}

// ---------------- xpart GEMM with XCD panel swizzle ----------------
// 1D grid 16384; the 16 N-tiles of one M-panel land on consecutive slots of
// one XCD (round-robin dispatch) -> A-panel reused from that XCD's L2.
__global__ __launch_bounds__(256) void gemm_xpart_kernel(
    const short* __restrict__ A, const short* __restrict__ Bt,
    const float* __restrict__ bias, short* __restrict__ Co){
  __shared__ short As[128*32];
  __shared__ short Bs[128*32];
  const int wg = blockIdx.x;
  const int xcd = wg & 7;
  const int ii = wg >> 3;                       // 0..2047 per xcd
  const long m0 = (long)(xcd*128 + (ii >> 4)) << 7;
  const long n0 = (long)(ii & 15) << 7;
  const int tid = threadIdx.x;
  const int lane = tid & 63;
  const int wave = tid >> 6;
  const int wm = wave & 1, wn = wave >> 1;
  f32x4 acc[4][4] = {};
  const int srow = tid >> 2;
  const int sseg = tid & 3;
  const long aoff = (m0 + srow) * 512 + sseg * 8;
  const long boff = (n0 + srow) * 512 + sseg * 8;
  short* ldsa = &As[tid * 8];
  short* ldsb = &Bs[tid * 8];
  for (int k0 = 0; k0 < 512; k0 += 32){
    __syncthreads();
    GLD16(A + aoff + k0, ldsa);
    GLD16(A + aoff + 64*512 + k0, ldsa + 2048);
    GLD16(Bt + boff + k0, ldsb);
    GLD16(Bt + boff + 64*512 + k0, ldsb + 2048);
    __syncthreads();
    const int kb = (lane >> 4) * 8;
    short8 af[4], bf[4];
    #pragma unroll
    for (int mi = 0; mi < 4; mi++) af[mi] = *(const short8*)&As[(wm*64 + mi*16 + (lane&15))*32 + kb];
    #pragma unroll
    for (int ni = 0; ni < 4; ni++) bf[ni] = *(const short8*)&Bs[(wn*64 + ni*16 + (lane&15))*32 + kb];
    #pragma unroll
    for (int mi = 0; mi < 4; mi++)
      #pragma unroll
      for (int ni = 0; ni < 4; ni++)
        acc[mi][ni] = __builtin_amdgcn_mfma_f32_16x16x32_bf16(af[mi], bf[ni], acc[mi][ni], 0, 0, 0);
  }
  #pragma unroll
  for (int ni = 0; ni < 4; ni++){
    const long col = n0 + wn*64 + ni*16 + (lane & 15);
    const float bv = bias[col];
    #pragma unroll
    for (int mi = 0; mi < 4; mi++){
      const long row = m0 + wm*64 + mi*16 + ((lane >> 4) << 2);
      #pragma unroll
      for (int r = 0; r < 4; r++)
        Co[(row + r)*ZN + col] = f2bf(acc[mi][ni][r] + bv);
    }
  }
}

// ---------------- persistent LSTM recurrence ----------------
// 256 WGs x 512 thr: bg = blockIdx&15 (16 rows), cg = blockIdx>>4 (32 ucols).
// Wave wv owns 16 z-cols = gate (wv>>1) x 16 ucols, FULL K=512 in registers
// (B-frags 64 VGPR) -> complete z per wave, no cross-K reduce. Gate exchange
// via tiny LDS (stride-19, conflict-light). Barrier: per-bg flag line, tid0
// fire-and-forget release store; every wave polls all 16 flags; out-store +
// xpart prefetch overlap the poll.
__global__ __launch_bounds__(512, 2) void lstm_persist_kernel(
    const short* __restrict__ xpart, const float* __restrict__ dones,
    const short* __restrict__ wht, short* __restrict__ hb0,
    short* __restrict__ hb1, unsigned* __restrict__ flags,
    float* __restrict__ out){
  __shared__ float zpart[128*19 + 16];   // [zl]*19 + row
  const int tid = threadIdx.x;
  const int lane = tid & 63;
  const int wv = tid >> 6;          // 0..7
  const int bg = blockIdx.x & 15;
  const int cg = blockIdx.x >> 4;   // 0..15
  const int rb = bg << 4;           // batch row base
  const int uc = cg << 5;           // u-col base (32 per WG)
  const int j = lane & 15;
  const int hq = lane >> 4;
  const int g_w = wv >> 1;                    // gate this wave computes
  const int ucl = ((wv & 1) << 4) + j;        // local ucol of this lane's B-col
  const int zl = g_w*32 + ucl;                // local z-col 0..127

  // ---- loop-invariant B fragments: wht[512*g_w + uc + ucl][k], k=m*32+hq*8 ----
  short8 bfr[16];
  {
    const short* wsrc = wht + ((long)(g_w*512 + uc + ucl))*512 + hq*8;
    #pragma unroll
    for (int m = 0; m < 16; m++)
      bfr[m] = *(const short8*)(wsrc + m*32);
  }

  // ---- epilogue mapping: one (row,ucol) per thread ----
  const int erow = tid >> 5;        // 0..15
  const int euj  = tid & 31;        // 0..31
  const int eucol = uc + euj;
  const int row  = rb + erow;

  unsigned* fl = flags + bg*16;
  const unsigned short* xp16 = (const unsigned short*)xpart;

  float c = 0.0f;
  float dn;
  unsigned short xp[4];
  dn = dones[(long)row*TT + 0];
  #pragma unroll
  for (int g = 0; g < 4; g++)
    xp[g] = xp16[((long)0*BATCH + row)*ZN + (g<<9) + eucol];

  const short* habase0 = hb0 + (long)(rb + j)*UU + hq*8;
  const short* habase1 = hb1 + (long)(rb + j)*UU + hq*8;

  for (int t = 0; t < TT; t++){
    // ---- A fragments: full K=512 of h rows rb..rb+15 ----
    const short* ab = (t & 1) ? habase1 : habase0;
    short8 a[16];
    CLOAD(a[0],  ab, "0");   CLOAD(a[1],  ab, "64");
    CLOAD(a[2],  ab, "128"); CLOAD(a[3],  ab, "192");
    CLOAD(a[4],  ab, "256"); CLOAD(a[5],  ab, "320");
    CLOAD(a[6],  ab, "384"); CLOAD(a[7],  ab, "448");
    CLOAD(a[8],  ab, "512"); CLOAD(a[9],  ab, "576");
    CLOAD(a[10], ab, "640"); CLOAD(a[11], ab, "704");
    CLOAD(a[12], ab, "768"); CLOAD(a[13], ab, "832");
    CLOAD(a[14], ab, "896"); CLOAD(a[15], ab, "960");
    f32x4 acc = {};
    asm volatile("s_waitcnt vmcnt(8)" ::: "memory");
    __builtin_amdgcn_sched_barrier(0);
    #pragma unroll
    for (int m = 0; m < 8; m++)
      acc = __builtin_amdgcn_mfma_f32_16x16x32_bf16(a[m], bfr[m], acc, 0, 0, 0);
    asm volatile("s_waitcnt vmcnt(0)" ::: "memory");
    __builtin_amdgcn_sched_barrier(0);
    #pragma unroll
    for (int m = 8; m < 16; m++)
      acc = __builtin_amdgcn_mfma_f32_16x16x32_bf16(a[m], bfr[m], acc, 0, 0, 0);
    // ---- publish z (4 x b32, stride-19 layout) ----
    #pragma unroll
    for (int r = 0; r < 4; r++)
      zpart[zl*19 + hq*4 + r] = acc[r];
    __syncthreads();
    // ---- gates (one (row,ucol) per thread) ----
    const float keep = 1.0f - dn;
    const float cold = c * keep;
    const float z0 = bf2f(xp[0]) + keep*zpart[(0*32 + euj)*19 + erow];
    const float z1 = bf2f(xp[1]) + keep*zpart[(1*32 + euj)*19 + erow];
    const float z2 = bf2f(xp[2]) + keep*zpart[(2*32 + euj)*19 + erow];
    const float z3 = bf2f(xp[3]) + keep*zpart[(3*32 + euj)*19 + erow];
    const float gi = sigm(z0);
    const float gf = sigm(z1);
    const float go = sigm(z2);
    const float gu = tanh_fast(z3);
    const float cn = gf*cold + gi*gu;
    const float hn = go * tanh_fast(cn);
    c = cn;
    if (t == TT-1){
      out[(long)row*TT*UU + (long)t*UU + eucol] = hn;
      float* s = out + (long)BATCH*TT*UU;
      s[(long)row*2*UU + eucol] = cn;
      s[(long)row*2*UU + UU + eucol] = hn;
    } else {
      // h-store first; drain ONLY it before release
      short* hdst = (t & 1) ? hb0 : hb1;
      st_coh_u16(hdst + (long)row*UU + eucol, (unsigned)(unsigned short)f2bf(hn));
      asm volatile("s_waitcnt vmcnt(0)" ::: "memory");
      __syncthreads();                      // whole WG's h(t+1) is in MALL
      if (tid == 0) st_coh_u32(fl + cg, (unsigned)(t+1));   // release
      // out-store + next-step prefetch drain during the poll
      out[(long)row*TT*UU + (long)t*UU + eucol] = hn;
      dn = dones[(long)row*TT + (t+1)];
      #pragma unroll
      for (int g = 0; g < 4; g++)
        xp[g] = xp16[((long)(t+1)*BATCH + row)*ZN + (g<<9) + eucol];
      // every wave polls all 16 flags of its bg
      const unsigned tgt = (unsigned)(t+1);
      unsigned v;
      do {
        CLOADW(v, fl + (lane & 15));
        asm volatile("s_waitcnt vmcnt(0)" ::: "memory");
      } while (!__all((int)(v >= tgt)));
      __builtin_amdgcn_sched_barrier(0);
    }
  }
}

extern "C" void kernel_launch(void* const* d_in, const int* in_sizes, int n_in,
                              void* d_out, int out_size, void* d_ws, size_t ws_size,
                              hipStream_t stream){
  const float* x     = (const float*)d_in[0];
  const float* dones = (const float*)d_in[1];
  const float* wx    = (const float*)d_in[2];
  const float* wh    = (const float*)d_in[3];
  const float* b     = (const float*)d_in[4];
  float* out = (float*)d_out;
  char* ws = (char*)d_ws;
  short* x_tb  = (short*)(ws);                    // 134,217,728 B
  short* wx_t  = (short*)(ws + 134217728L);       //   2,097,152 B
  short* wh_t  = (short*)(ws + 136314880L);       //   2,097,152 B
  short* xpart = (short*)(ws + 138412032L);       // 536,870,912 B
  short* hb0   = (short*)(ws + 675282944L);       //     262,144 B
  short* hb1   = (short*)(ws + 675545088L);       //     262,144 B
  unsigned* flags = (unsigned*)(ws + 675807232L); //       1,024 B

  hipMemsetAsync(hb0, 0, 262144, stream);
  hipMemsetAsync(flags, 0, 1024, stream);
  convert_x_kernel<<<2048, 256, 0, stream>>>(x, x_tb);
  transpose_w_kernel<<<dim3(64,16,2), 256, 0, stream>>>(wx, wh, wx_t, wh_t);
  gemm_xpart_kernel<<<16384, 256, 0, stream>>>(x_tb, wx_t, b, xpart);
  lstm_persist_kernel<<<256, 512, 0, stream>>>(xpart, dones, wh_t, hb0, hb1, flags, out);
}

// Round 5
// 1856.060 us; speedup vs baseline: 1.9018x; 1.9018x over previous
//
#include <hip/hip_runtime.h>

#define BATCH 256
#define TT 512
#define CIN 512
#define UU 512
#define ZN 2048
#define BT (BATCH*TT)
#define NWGPB 16   // WGs per batch-group barrier

typedef __attribute__((ext_vector_type(8))) short short8;
typedef __attribute__((ext_vector_type(4))) float f32x4;

__device__ __forceinline__ short f2bf(float f){
  unsigned u = __float_as_uint(f);
  u += 0x7fffu + ((u >> 16) & 1u);   // round-to-nearest-even
  return (short)(u >> 16);
}
__device__ __forceinline__ float bf2f(unsigned short s){
  unsigned u = ((unsigned)s) << 16;
  return __uint_as_float(u);
}

#define GLD16(g, l) __builtin_amdgcn_global_load_lds( \
    (const __attribute__((address_space(1))) void*)(g), \
    (__attribute__((address_space(3))) void*)(l), 16, 0, 0)

// coherent (device-scope, MALL) 16B load with immediate offset
#define CLOAD(dst, p, OFFSTR) asm volatile( \
    "global_load_dwordx4 %0, %1, off offset:" OFFSTR " sc0 sc1" \
    : "=v"(dst) : "v"(p) : "memory")
// coherent 4B load
#define CLOADW(dst, p) asm volatile( \
    "global_load_dword %0, %1, off sc0 sc1" \
    : "=v"(dst) : "v"(p) : "memory")

__device__ __forceinline__ void st_coh_u16(void* p, unsigned v){
  asm volatile("global_store_short %0, %1, off sc0 sc1" :: "v"(p), "v"(v) : "memory");
}
__device__ __forceinline__ void st_coh_u32(void* p, unsigned v){
  asm volatile("global_store_dword %0, %1, off sc0 sc1" :: "v"(p), "v"(v) : "memory");
}

__device__ __forceinline__ float sigm(float x){ return 1.0f/(1.0f + __expf(-x)); }
__device__ __forceinline__ float tanh_fast(float x){ return 1.0f - 2.0f/(1.0f + __expf(2.0f*x)); }

// ---------------- convert x [B][T][C] f32 -> x_tb [(t*B+b)][C] bf16 ----------------
__global__ __launch_bounds__(256) void convert_x_kernel(const float* __restrict__ x,
                                                        short* __restrict__ xb){
  const long total = (long)TT*BATCH*64;   // 8-elem chunks
  const long stride = (long)gridDim.x * blockDim.x;
  for (long i = (long)blockIdx.x * blockDim.x + threadIdx.x; i < total; i += stride){
    const int c8 = (int)(i & 63);
    const long tb = i >> 6;
    const int b = (int)(tb & (BATCH-1));
    const int t = (int)(tb >> 8);
    const float* src = x + ((long)b*TT + t)*CIN + c8*8;
    const float4 v0 = *(const float4*)(src);
    const float4 v1 = *(const float4*)(src + 4);
    short8 o;
    o[0]=f2bf(v0.x); o[1]=f2bf(v0.y); o[2]=f2bf(v0.z); o[3]=f2bf(v0.w);
    o[4]=f2bf(v1.x); o[5]=f2bf(v1.y); o[6]=f2bf(v1.z); o[7]=f2bf(v1.w);
    *(short8*)(xb + i*8) = o;
  }
}

// ---------------- transpose wx/wh: [512][2048] f32 -> [2048][512] bf16 ----------------
__global__ __launch_bounds__(256) void transpose_w_kernel(
    const float* __restrict__ wx, const float* __restrict__ wh,
    short* __restrict__ wxt, short* __restrict__ wht){
  const float* src = blockIdx.z ? wh : wx;
  short* dst = blockIdx.z ? wht : wxt;
  __shared__ float tile[32][33];
  const int nt = blockIdx.x << 5;
  const int kt = blockIdx.y << 5;
  const int tx = threadIdx.x & 31, ty = threadIdx.x >> 5;
  #pragma unroll
  for (int i = 0; i < 32; i += 8)
    tile[ty+i][tx] = src[(long)(kt+ty+i)*ZN + nt+tx];
  __syncthreads();
  #pragma unroll
  for (int i = 0; i < 32; i += 8)
    dst[(long)(nt+ty+i)*512 + kt+tx] = f2bf(tile[tx][ty+i]);
}

// ---------------- xpart GEMM with XCD panel swizzle ----------------
__global__ __launch_bounds__(256) void gemm_xpart_kernel(
    const short* __restrict__ A, const short* __restrict__ Bt,
    const float* __restrict__ bias, short* __restrict__ Co){
  __shared__ short As[128*32];
  __shared__ short Bs[128*32];
  const int wg = blockIdx.x;
  const int xcd = wg & 7;
  const int ii = wg >> 3;                       // 0..2047 per xcd
  const long m0 = (long)(xcd*128 + (ii >> 4)) << 7;
  const long n0 = (long)(ii & 15) << 7;
  const int tid = threadIdx.x;
  const int lane = tid & 63;
  const int wave = tid >> 6;
  const int wm = wave & 1, wn = wave >> 1;
  f32x4 acc[4][4] = {};
  const int srow = tid >> 2;
  const int sseg = tid & 3;
  const long aoff = (m0 + srow) * 512 + sseg * 8;
  const long boff = (n0 + srow) * 512 + sseg * 8;
  short* ldsa = &As[tid * 8];
  short* ldsb = &Bs[tid * 8];
  for (int k0 = 0; k0 < 512; k0 += 32){
    __syncthreads();
    GLD16(A + aoff + k0, ldsa);
    GLD16(A + aoff + 64*512 + k0, ldsa + 2048);
    GLD16(Bt + boff + k0, ldsb);
    GLD16(Bt + boff + 64*512 + k0, ldsb + 2048);
    __syncthreads();
    const int kb = (lane >> 4) * 8;
    short8 af[4], bf[4];
    #pragma unroll
    for (int mi = 0; mi < 4; mi++) af[mi] = *(const short8*)&As[(wm*64 + mi*16 + (lane&15))*32 + kb];
    #pragma unroll
    for (int ni = 0; ni < 4; ni++) bf[ni] = *(const short8*)&Bs[(wn*64 + ni*16 + (lane&15))*32 + kb];
    #pragma unroll
    for (int mi = 0; mi < 4; mi++)
      #pragma unroll
      for (int ni = 0; ni < 4; ni++)
        acc[mi][ni] = __builtin_amdgcn_mfma_f32_16x16x32_bf16(af[mi], bf[ni], acc[mi][ni], 0, 0, 0);
  }
  #pragma unroll
  for (int ni = 0; ni < 4; ni++){
    const long col = n0 + wn*64 + ni*16 + (lane & 15);
    const float bv = bias[col];
    #pragma unroll
    for (int mi = 0; mi < 4; mi++){
      const long row = m0 + wm*64 + mi*16 + ((lane >> 4) << 2);
      #pragma unroll
      for (int r = 0; r < 4; r++)
        Co[(row + r)*ZN + col] = f2bf(acc[mi][ni][r] + bv);
    }
  }
}

// ---------------- persistent LSTM recurrence ----------------
// 256 WGs x 512 thr: bg = blockIdx&15 (16 rows), cg = blockIdx>>4 (32 ucols).
// Wave wv owns 16 z-cols = gate (wv>>1) x 16 ucols, FULL K=512 register-held
// wh (64 VGPR). h(t) staged ONCE per WG into XOR-swizzled LDS (coherent
// cooperative load), A-frags via ds_read_b128 (2-way = free). Barrier: store
// h(sc1) -> vmcnt(0) -> sync -> tid0 flag store; wave0 polls 16 flags with
// s_sleep backoff; syncthreads release. out-store + xpart prefetch overlap.
__global__ __launch_bounds__(512, 2) void lstm_persist_kernel(
    const short* __restrict__ xpart, const float* __restrict__ dones,
    const short* __restrict__ wht, short* __restrict__ hb0,
    short* __restrict__ hb1, unsigned* __restrict__ flags,
    float* __restrict__ out){
  __shared__ short h_lds[8192];          // 16 rows x 512 cols, XOR-swizzled
  __shared__ float zpart[128*19 + 16];
  const int tid = threadIdx.x;
  const int lane = tid & 63;
  const int wv = tid >> 6;          // 0..7
  const int bg = blockIdx.x & 15;
  const int cg = blockIdx.x >> 4;   // 0..15
  const int rb = bg << 4;           // batch row base
  const int uc = cg << 5;           // u-col base (32 per WG)
  const int j = lane & 15;
  const int hq = lane >> 4;
  const int g_w = wv >> 1;                    // gate this wave computes
  const int ucl = ((wv & 1) << 4) + j;        // local ucol of this lane's B-col
  const int zl = g_w*32 + ucl;                // local z-col 0..127

  // ---- loop-invariant B fragments: wht[512*g_w + uc + ucl][k], k=m*32+hq*8 ----
  short8 bfr[16];
  {
    const short* wsrc = wht + ((long)(g_w*512 + uc + ucl))*512 + hq*8;
    #pragma unroll
    for (int m = 0; m < 16; m++)
      bfr[m] = *(const short8*)(wsrc + m*32);
  }

  // ---- staging mapping: thread -> (row, 16-col chunk x2) ----
  const int srow = tid >> 5;          // 0..15
  const int scol = (tid & 31) << 4;   // bf16 col base (32B per thread)
  const int swb = (srow << 10) + (scol << 1);          // byte base in h_lds
  const int sxor = (srow & 7) << 4;
  // ---- A-frag read base: row j, k = m*64B + hq*16B ----
  const int arb = (j << 10) + (hq << 4);
  const int axor = (j & 7) << 4;

  // ---- epilogue mapping: one (row,ucol) per thread ----
  const int erow = tid >> 5;        // 0..15
  const int euj  = tid & 31;        // 0..31
  const int eucol = uc + euj;
  const int row  = rb + erow;

  unsigned* fl = flags + bg*16;
  const unsigned short* xp16 = (const unsigned short*)xpart;

  float c = 0.0f;
  float dn;
  unsigned short xp[4];
  dn = dones[(long)row*TT + 0];
  #pragma unroll
  for (int g = 0; g < 4; g++)
    xp[g] = xp16[((long)0*BATCH + row)*ZN + (g<<9) + eucol];

  for (int t = 0; t < TT; t++){
    // ---- stage h(t) -> LDS (coherent read; h(t) visibility guaranteed by
    //      previous step's barrier; t=0 reads memset zeros) ----
    {
      const short* hsrc = ((t & 1) ? hb1 : hb0) + (long)(rb + srow)*UU + scol;
      short8 hv0, hv1;
      CLOAD(hv0, hsrc, "0");
      CLOAD(hv1, hsrc, "16");
      asm volatile("s_waitcnt vmcnt(0)" ::: "memory");
      *(short8*)((char*)h_lds + ( swb       ^ sxor)) = hv0;
      *(short8*)((char*)h_lds + ((swb + 16) ^ sxor)) = hv1;
    }
    __syncthreads();
    // ---- A-frags from LDS + 2-chain MFMA ----
    short8 a[16];
    #pragma unroll
    for (int m = 0; m < 16; m++)
      a[m] = *(const short8*)((const char*)h_lds + ((arb + (m << 6)) ^ axor));
    f32x4 acc0 = {}, acc1 = {};
    #pragma unroll
    for (int m = 0; m < 16; m += 2){
      acc0 = __builtin_amdgcn_mfma_f32_16x16x32_bf16(a[m],   bfr[m],   acc0, 0, 0, 0);
      acc1 = __builtin_amdgcn_mfma_f32_16x16x32_bf16(a[m+1], bfr[m+1], acc1, 0, 0, 0);
    }
    const f32x4 acc = acc0 + acc1;
    // ---- publish z (stride-19 layout, conflict-light) ----
    #pragma unroll
    for (int r = 0; r < 4; r++)
      zpart[zl*19 + hq*4 + r] = acc[r];
    __syncthreads();
    // ---- gates (one (row,ucol) per thread) ----
    const float keep = 1.0f - dn;
    const float cold = c * keep;
    const float z0 = bf2f(xp[0]) + keep*zpart[(0*32 + euj)*19 + erow];
    const float z1 = bf2f(xp[1]) + keep*zpart[(1*32 + euj)*19 + erow];
    const float z2 = bf2f(xp[2]) + keep*zpart[(2*32 + euj)*19 + erow];
    const float z3 = bf2f(xp[3]) + keep*zpart[(3*32 + euj)*19 + erow];
    const float gi = sigm(z0);
    const float gf = sigm(z1);
    const float go = sigm(z2);
    const float gu = tanh_fast(z3);
    const float cn = gf*cold + gi*gu;
    const float hn = go * tanh_fast(cn);
    c = cn;
    if (t == TT-1){
      out[(long)row*TT*UU + (long)t*UU + eucol] = hn;
      float* s = out + (long)BATCH*TT*UU;
      s[(long)row*2*UU + eucol] = cn;
      s[(long)row*2*UU + UU + eucol] = hn;
    } else {
      // release: h(t+1) store -> drain -> WG sync -> flag
      short* hdst = (t & 1) ? hb0 : hb1;
      st_coh_u16(hdst + (long)row*UU + eucol, (unsigned)(unsigned short)f2bf(hn));
      asm volatile("s_waitcnt vmcnt(0)" ::: "memory");
      __syncthreads();                      // also protects h_lds reuse
      if (tid == 0) st_coh_u32(fl + cg, (unsigned)(t+1));
      // overlap: out-store + next-step prefetch
      out[(long)row*TT*UU + (long)t*UU + eucol] = hn;
      dn = dones[(long)row*TT + (t+1)];
      #pragma unroll
      for (int g = 0; g < 4; g++)
        xp[g] = xp16[((long)(t+1)*BATCH + row)*ZN + (g<<9) + eucol];
      // single-wave poll of the bg's 16 flags, with backoff
      if (wv == 0){
        const unsigned tgt = (unsigned)(t+1);
        unsigned v;
        for (;;){
          CLOADW(v, fl + (lane & 15));
          asm volatile("s_waitcnt vmcnt(0)" ::: "memory");
          if (__all((int)(v >= tgt))) break;
          __builtin_amdgcn_s_sleep(1);
        }
      }
      __syncthreads();                      // release all waves
    }
  }
}

extern "C" void kernel_launch(void* const* d_in, const int* in_sizes, int n_in,
                              void* d_out, int out_size, void* d_ws, size_t ws_size,
                              hipStream_t stream){
  const float* x     = (const float*)d_in[0];
  const float* dones = (const float*)d_in[1];
  const float* wx    = (const float*)d_in[2];
  const float* wh    = (const float*)d_in[3];
  const float* b     = (const float*)d_in[4];
  float* out = (float*)d_out;
  char* ws = (char*)d_ws;
  short* x_tb  = (short*)(ws);                    // 134,217,728 B
  short* wx_t  = (short*)(ws + 134217728L);       //   2,097,152 B
  short* wh_t  = (short*)(ws + 136314880L);       //   2,097,152 B
  short* xpart = (short*)(ws + 138412032L);       // 536,870,912 B
  short* hb0   = (short*)(ws + 675282944L);       //     262,144 B
  short* hb1   = (short*)(ws + 675545088L);       //     262,144 B
  unsigned* flags = (unsigned*)(ws + 675807232L); //       1,024 B

  hipMemsetAsync(hb0, 0, 262144, stream);
  hipMemsetAsync(flags, 0, 1024, stream);
  convert_x_kernel<<<2048, 256, 0, stream>>>(x, x_tb);
  transpose_w_kernel<<<dim3(64,16,2), 256, 0, stream>>>(wx, wh, wx_t, wh_t);
  gemm_xpart_kernel<<<16384, 256, 0, stream>>>(x_tb, wx_t, b, xpart);
  lstm_persist_kernel<<<256, 512, 0, stream>>>(xpart, dones, wh_t, hb0, hb1, flags, out);
}